// Round 1
// baseline (1033.174 us; speedup 1.0000x reference)
//
#include <hip/hip_runtime.h>
#include <hip/hip_bf16.h>

typedef __bf16 bf16_t;
typedef __bf16 bf16x8 __attribute__((ext_vector_type(8)));
typedef __bf16 bf16x4v __attribute__((ext_vector_type(4)));
typedef float f32x4 __attribute__((ext_vector_type(4)));

#define HIDDEN 3584
#define SEQ 2048
#define NHEADS 28
#define NKV 4
#define HDIM 128
#define GROUPS 7
#define SCALING 0.08838834764831845f

__device__ inline f32x4 mfma16(bf16x8 a, bf16x8 b, f32x4 c) {
    return __builtin_amdgcn_mfma_f32_16x16x32_bf16(a, b, c, 0, 0, 0);
}

// async global->LDS, 16B per lane; lds dest must be wave-uniform base (+lane*16 done by HW)
__device__ inline void gl_lds16(const bf16_t* g, bf16_t* l) {
    __builtin_amdgcn_global_load_lds(
        (const __attribute__((address_space(1))) void*)g,
        (__attribute__((address_space(3))) void*)l, 16, 0, 0);
}

// ---------------- fp32 -> bf16 convert ----------------
__global__ void cvt_kernel(const float* __restrict__ src, bf16_t* __restrict__ dst, int n4) {
    int i = blockIdx.x * 256 + threadIdx.x;
    if (i < n4) {
        float4 f = ((const float4*)src)[i];
        bf16x4v o;
        o.x = (bf16_t)f.x; o.y = (bf16_t)f.y; o.z = (bf16_t)f.z; o.w = (bf16_t)f.w;
        ((bf16x4v*)dst)[i] = o;
    }
}

// ---------------- GEMM: C[M,N] = A[M,K] @ B[N,K]^T (+bias) ----------------
// 128x128 tile, BK=32, 256 threads (4 waves), each wave 64x64 via 4x4 MFMA 16x16x32
template <bool OUT_BF16>
__global__ __launch_bounds__(256) void gemm_bt(
    const bf16_t* __restrict__ A, const bf16_t* __restrict__ B,
    const float* __restrict__ bias, void* __restrict__ Cout,
    int M, int N, int K) {
    __shared__ __align__(16) bf16_t As[128 * 32];
    __shared__ __align__(16) bf16_t Bs[128 * 32];
    const int tid = threadIdx.x;
    const int w = tid >> 6, lane = tid & 63;
    const int quad = lane >> 4, l16 = lane & 15;
    const int wm = w >> 1, wn = w & 1;
    const int m0 = blockIdx.y * 128, n0 = blockIdx.x * 128;
    f32x4 acc[4][4] = {};
    for (int k0 = 0; k0 < K; k0 += 32) {
        __syncthreads();
        // stage 128x32 A and B tiles: 512 16B-chunks each, 2 instrs/wave each
#pragma unroll
        for (int i = 0; i < 2; ++i) {
            int ca = (w * 2 + i) * 64 + lane;     // chunk id 0..511
            int row = ca >> 2, kc = ca & 3;       // 4 chunks of 8 bf16 per row
            gl_lds16(A + (size_t)(m0 + row) * K + k0 + kc * 8, As + (size_t)(w * 2 + i) * 64 * 8);
            gl_lds16(B + (size_t)(n0 + row) * K + k0 + kc * 8, Bs + (size_t)(w * 2 + i) * 64 * 8);
        }
        __syncthreads();
        bf16x8 a[4], b[4];
#pragma unroll
        for (int i = 0; i < 4; ++i)
            a[i] = *(const bf16x8*)(As + (wm * 64 + i * 16 + l16) * 32 + quad * 8);
#pragma unroll
        for (int j = 0; j < 4; ++j)
            b[j] = *(const bf16x8*)(Bs + (wn * 64 + j * 16 + l16) * 32 + quad * 8);
#pragma unroll
        for (int i = 0; i < 4; ++i)
#pragma unroll
            for (int j = 0; j < 4; ++j)
                acc[i][j] = mfma16(a[i], b[j], acc[i][j]);
    }
    // epilogue: C/D layout col=lane&15, row=quad*4+reg
#pragma unroll
    for (int i = 0; i < 4; ++i) {
#pragma unroll
        for (int j = 0; j < 4; ++j) {
            int col = n0 + wn * 64 + j * 16 + l16;
            float bv_ = bias ? bias[col] : 0.f;
#pragma unroll
            for (int r = 0; r < 4; ++r) {
                int row = m0 + wm * 64 + i * 16 + quad * 4 + r;
                float v = acc[i][j][r] + bv_;
                if (OUT_BF16) ((bf16_t*)Cout)[(size_t)row * N + col] = (bf16_t)v;
                else          ((float*)Cout)[(size_t)row * N + col] = v;
            }
        }
    }
}

// ---------------- RoPE (in-place on bf16 q,k) ----------------
__global__ void rope_kernel(bf16_t* __restrict__ q, bf16_t* __restrict__ k,
                            const float* __restrict__ cosb, const float* __restrict__ sinb) {
    int t = blockIdx.x * 256 + threadIdx.x;   // SEQ * 32 * 64 total
    int d = t & 63;
    int hh = (t >> 6) & 31;
    int s = t >> 11;
    float c0 = cosb[s * 128 + d], sn0 = sinb[s * 128 + d];
    float c1 = cosb[s * 128 + d + 64], sn1 = sinb[s * 128 + d + 64];
    bf16_t* p;
    if (hh < NHEADS) p = q + (size_t)s * (NHEADS * HDIM) + hh * HDIM;
    else             p = k + (size_t)s * (NKV * HDIM) + (hh - NHEADS) * HDIM;
    float x0 = (float)p[d], x1 = (float)p[d + 64];
    p[d]      = (bf16_t)(x0 * c0 - x1 * sn0);
    p[d + 64] = (bf16_t)(x1 * c1 + x0 * sn1);
}

// ---------------- Flash attention, causal, GQA ----------------
// grid (SEQ/64, NHEADS); 4 waves; wave w owns Q rows qb*64+w*16..+16
__global__ __launch_bounds__(256) void attn_kernel(
    const bf16_t* __restrict__ q, const bf16_t* __restrict__ k,
    const bf16_t* __restrict__ v, bf16_t* __restrict__ o_out) {
    __shared__ __align__(16) bf16_t Ks[32][128];   // kv rows x d
    __shared__ __align__(16) bf16_t Vt[128][32];   // transposed: d x kv
    __shared__ __align__(16) bf16_t Pb[4][16][32]; // per-wave P tile
    const int tid = threadIdx.x;
    const int w = tid >> 6, lane = tid & 63;
    const int quad = lane >> 4, l16 = lane & 15;
    const int qb = blockIdx.x, h = blockIdx.y;
    const int kvh = h / GROUPS;
    const int row_q = qb * 64 + w * 16 + l16;
    bf16x8 qa[4];
#pragma unroll
    for (int kc = 0; kc < 4; ++kc)
        qa[kc] = *(const bf16x8*)(q + (size_t)row_q * (NHEADS * HDIM) + h * HDIM + kc * 32 + quad * 8);
    f32x4 o[8] = {};
    float m_r[4], l_r[4];
#pragma unroll
    for (int r = 0; r < 4; ++r) { m_r[r] = -3.0e38f; l_r[r] = 0.f; }
    const int ntiles = qb * 2 + 2;
    for (int it = 0; it < ntiles; ++it) {
        const int kv0 = it * 32;
        __syncthreads();
        // cooperative stage: K tile row-major, V tile transposed
#pragma unroll
        for (int c = 0; c < 2; ++c) {
            int chunk = tid + c * 256;            // 512 chunks of 8 bf16
            int r = chunk >> 4, c8 = chunk & 15;
            *(int4*)&Ks[r][c8 * 8] = *(const int4*)(k + (size_t)(kv0 + r) * (NKV * HDIM) + kvh * HDIM + c8 * 8);
            int4 tmp = *(const int4*)(v + (size_t)(kv0 + r) * (NKV * HDIM) + kvh * HDIM + c8 * 8);
            bf16_t* ts = (bf16_t*)&tmp;
#pragma unroll
            for (int i2 = 0; i2 < 8; ++i2) Vt[c8 * 8 + i2][r] = ts[i2];
        }
        __syncthreads();
        // S = Q K^T  (16x32 per wave, two 16x16 C frags)
        f32x4 s0 = {}, s1 = {};
#pragma unroll
        for (int kc = 0; kc < 4; ++kc) {
            bf16x8 kb0 = *(const bf16x8*)&Ks[l16][kc * 32 + quad * 8];
            bf16x8 kb1 = *(const bf16x8*)&Ks[16 + l16][kc * 32 + quad * 8];
            s0 = mfma16(qa[kc], kb0, s0);
            s1 = mfma16(qa[kc], kb1, s1);
        }
        // online softmax
        float x0[4], x1[4], mx[4];
#pragma unroll
        for (int r = 0; r < 4; ++r) {
            int rowg = qb * 64 + w * 16 + quad * 4 + r;
            x0[r] = s0[r] * SCALING;
            x1[r] = s1[r] * SCALING;
            if (kv0 + l16 > rowg)      x0[r] = -3.0e38f;
            if (kv0 + 16 + l16 > rowg) x1[r] = -3.0e38f;
            mx[r] = fmaxf(x0[r], x1[r]);
        }
#pragma unroll
        for (int off = 1; off < 16; off <<= 1)
#pragma unroll
            for (int r = 0; r < 4; ++r)
                mx[r] = fmaxf(mx[r], __shfl_xor(mx[r], off));
        float al[4], p0[4], p1[4], rs[4];
#pragma unroll
        for (int r = 0; r < 4; ++r) {
            float mn = fmaxf(m_r[r], mx[r]);
            al[r] = __expf(m_r[r] - mn);
            p0[r] = __expf(x0[r] - mn);
            p1[r] = __expf(x1[r] - mn);
            m_r[r] = mn;
            rs[r] = p0[r] + p1[r];
        }
#pragma unroll
        for (int off = 1; off < 16; off <<= 1)
#pragma unroll
            for (int r = 0; r < 4; ++r)
                rs[r] += __shfl_xor(rs[r], off);
#pragma unroll
        for (int r = 0; r < 4; ++r) l_r[r] = al[r] * l_r[r] + rs[r];
#pragma unroll
        for (int nc = 0; nc < 8; ++nc)
#pragma unroll
            for (int r = 0; r < 4; ++r) o[nc][r] *= al[r];
        // P: C-layout -> LDS -> A-layout (same wave; LDS pipe is in-order per wave)
#pragma unroll
        for (int r = 0; r < 4; ++r) {
            Pb[w][quad * 4 + r][l16]      = (bf16_t)p0[r];
            Pb[w][quad * 4 + r][16 + l16] = (bf16_t)p1[r];
        }
        bf16x8 pa = *(const bf16x8*)&Pb[w][l16][quad * 8];
        // O += P V  (8 d-chunks of 16)
#pragma unroll
        for (int nc = 0; nc < 8; ++nc) {
            bf16x8 vb = *(const bf16x8*)&Vt[nc * 16 + l16][quad * 8];
            o[nc] = mfma16(pa, vb, o[nc]);
        }
    }
    // normalize + store (S, NHEADS*HDIM) bf16
#pragma unroll
    for (int nc = 0; nc < 8; ++nc)
#pragma unroll
        for (int r = 0; r < 4; ++r) {
            int rowg = qb * 64 + w * 16 + quad * 4 + r;
            int col = h * HDIM + nc * 16 + l16;
            o_out[(size_t)rowg * (NHEADS * HDIM) + col] = (bf16_t)(o[nc][r] / l_r[r]);
        }
}

extern "C" void kernel_launch(void* const* d_in, const int* in_sizes, int n_in,
                              void* d_out, int out_size, void* d_ws, size_t ws_size,
                              hipStream_t stream) {
    const float* hs   = (const float*)d_in[0];
    const float* cosb = (const float*)d_in[1];
    const float* sinb = (const float*)d_in[2];
    const float* Wq   = (const float*)d_in[3];
    const float* bq   = (const float*)d_in[4];
    const float* Wk   = (const float*)d_in[5];
    const float* bk   = (const float*)d_in[6];
    const float* Wv   = (const float*)d_in[7];
    const float* bv   = (const float*)d_in[8];
    const float* Wo   = (const float*)d_in[9];
    float* out = (float*)d_out;

    char* p = (char*)d_ws;
    bf16_t* hsb = (bf16_t*)p; p += (size_t)SEQ * HIDDEN * 2;
    bf16_t* Wqb = (bf16_t*)p; p += (size_t)HIDDEN * HIDDEN * 2;
    bf16_t* Wkb = (bf16_t*)p; p += (size_t)(NKV * HDIM) * HIDDEN * 2;
    bf16_t* Wvb = (bf16_t*)p; p += (size_t)(NKV * HDIM) * HIDDEN * 2;
    bf16_t* Wob = (bf16_t*)p; p += (size_t)HIDDEN * HIDDEN * 2;
    bf16_t* qb_ = (bf16_t*)p; p += (size_t)SEQ * (NHEADS * HDIM) * 2;
    bf16_t* kb_ = (bf16_t*)p; p += (size_t)SEQ * (NKV * HDIM) * 2;
    bf16_t* vb_ = (bf16_t*)p; p += (size_t)SEQ * (NKV * HDIM) * 2;
    bf16_t* ab_ = Wqb;  // alias: Wq(bf16) is dead after the Q GEMM; attn runs after

    auto cvt = [&](const float* s, bf16_t* d, size_t n) {
        int n4 = (int)(n / 4);
        cvt_kernel<<<(n4 + 255) / 256, 256, 0, stream>>>(s, d, n4);
    };
    cvt(hs, hsb, (size_t)SEQ * HIDDEN);
    cvt(Wq, Wqb, (size_t)HIDDEN * HIDDEN);
    cvt(Wk, Wkb, (size_t)(NKV * HDIM) * HIDDEN);
    cvt(Wv, Wvb, (size_t)(NKV * HDIM) * HIDDEN);
    cvt(Wo, Wob, (size_t)HIDDEN * HIDDEN);

    gemm_bt<true><<<dim3((NHEADS * HDIM) / 128, SEQ / 128), 256, 0, stream>>>(
        hsb, Wqb, bq, qb_, SEQ, NHEADS * HDIM, HIDDEN);
    gemm_bt<true><<<dim3((NKV * HDIM) / 128, SEQ / 128), 256, 0, stream>>>(
        hsb, Wkb, bk, kb_, SEQ, NKV * HDIM, HIDDEN);
    gemm_bt<true><<<dim3((NKV * HDIM) / 128, SEQ / 128), 256, 0, stream>>>(
        hsb, Wvb, bv, vb_, SEQ, NKV * HDIM, HIDDEN);

    rope_kernel<<<(SEQ * 32 * 64) / 256, 256, 0, stream>>>(qb_, kb_, cosb, sinb);

    attn_kernel<<<dim3(SEQ / 64, NHEADS), 256, 0, stream>>>(qb_, kb_, vb_, ab_);

    gemm_bt<false><<<dim3(HIDDEN / 128, SEQ / 128), 256, 0, stream>>>(
        ab_, Wob, nullptr, out, SEQ, HIDDEN, HIDDEN);
}

// Round 2
// 558.500 us; speedup vs baseline: 1.8499x; 1.8499x over previous
//
#include <hip/hip_runtime.h>
#include <hip/hip_bf16.h>

typedef __bf16 bf16_t;
typedef __bf16 bf16x8 __attribute__((ext_vector_type(8)));
typedef __bf16 bf16x4v __attribute__((ext_vector_type(4)));
typedef float f32x4 __attribute__((ext_vector_type(4)));

#define HIDDEN 3584
#define SEQ 2048
#define NHEADS 28
#define NKV 4
#define HDIM 128
#define GROUPS 7
#define QKV_LD 4608
#define SCALING 0.08838834764831845f
#define SCL_LOG2 (0.08838834764831845f * 1.44269504088896f)

__device__ inline f32x4 mfma16(bf16x8 a, bf16x8 b, f32x4 c) {
    return __builtin_amdgcn_mfma_f32_16x16x32_bf16(a, b, c, 0, 0, 0);
}

__device__ inline void gl_lds16(const bf16_t* g, bf16_t* l) {
    __builtin_amdgcn_global_load_lds(
        (const __attribute__((address_space(1))) void*)g,
        (__attribute__((address_space(3))) void*)l, 16, 0, 0);
}

// ---------------- fp32 -> bf16 convert ----------------
__global__ void cvt_kernel(const float* __restrict__ src, bf16_t* __restrict__ dst, int n4) {
    int i = blockIdx.x * 256 + threadIdx.x;
    if (i < n4) {
        float4 f = ((const float4*)src)[i];
        bf16x4v o;
        o.x = (bf16_t)f.x; o.y = (bf16_t)f.y; o.z = (bf16_t)f.z; o.w = (bf16_t)f.w;
        ((bf16x4v*)dst)[i] = o;
    }
}

// ---------------- bias concat (bq|bk|bv) ----------------
__global__ void bcat_kernel(const float* __restrict__ bq, const float* __restrict__ bk,
                            const float* __restrict__ bv, float* __restrict__ dst) {
    int i = blockIdx.x * 256 + threadIdx.x;
    if (i < QKV_LD) {
        float v = (i < HIDDEN) ? bq[i] : (i < HIDDEN + 512 ? bk[i - HIDDEN] : bv[i - HIDDEN - 512]);
        dst[i] = v;
    }
}

// ---------------- GEMM: C[M,N] = A[M,K] @ B[N,K]^T (+bias) ----------------
template <bool OUT_BF16>
__global__ __launch_bounds__(256) void gemm_bt(
    const bf16_t* __restrict__ A, const bf16_t* __restrict__ B,
    const float* __restrict__ bias, void* __restrict__ Cout,
    int M, int N, int K) {
    __shared__ __align__(16) bf16_t As[128 * 32];
    __shared__ __align__(16) bf16_t Bs[128 * 32];
    const int tid = threadIdx.x;
    const int w = tid >> 6, lane = tid & 63;
    const int quad = lane >> 4, l16 = lane & 15;
    const int wm = w >> 1, wn = w & 1;
    const int m0 = blockIdx.y * 128, n0 = blockIdx.x * 128;
    f32x4 acc[4][4] = {};
    for (int k0 = 0; k0 < K; k0 += 32) {
        __syncthreads();
#pragma unroll
        for (int i = 0; i < 2; ++i) {
            int ca = (w * 2 + i) * 64 + lane;
            int row = ca >> 2, kc = ca & 3;
            gl_lds16(A + (size_t)(m0 + row) * K + k0 + kc * 8, As + (size_t)(w * 2 + i) * 64 * 8);
            gl_lds16(B + (size_t)(n0 + row) * K + k0 + kc * 8, Bs + (size_t)(w * 2 + i) * 64 * 8);
        }
        __syncthreads();
        bf16x8 a[4], b[4];
#pragma unroll
        for (int i = 0; i < 4; ++i)
            a[i] = *(const bf16x8*)(As + (wm * 64 + i * 16 + l16) * 32 + quad * 8);
#pragma unroll
        for (int j = 0; j < 4; ++j)
            b[j] = *(const bf16x8*)(Bs + (wn * 64 + j * 16 + l16) * 32 + quad * 8);
#pragma unroll
        for (int i = 0; i < 4; ++i)
#pragma unroll
            for (int j = 0; j < 4; ++j)
                acc[i][j] = mfma16(a[i], b[j], acc[i][j]);
    }
#pragma unroll
    for (int i = 0; i < 4; ++i) {
#pragma unroll
        for (int j = 0; j < 4; ++j) {
            int col = n0 + wn * 64 + j * 16 + l16;
            float bv_ = bias ? bias[col] : 0.f;
#pragma unroll
            for (int r = 0; r < 4; ++r) {
                int row = m0 + wm * 64 + i * 16 + quad * 4 + r;
                float v = acc[i][j][r] + bv_;
                if (OUT_BF16) ((bf16_t*)Cout)[(size_t)row * N + col] = (bf16_t)v;
                else          ((float*)Cout)[(size_t)row * N + col] = v;
            }
        }
    }
}

// ---------------- RoPE (in-place on bf16 qkv buffer) ----------------
__global__ void rope_kernel(bf16_t* __restrict__ qkv,
                            const float* __restrict__ cosb, const float* __restrict__ sinb) {
    int t = blockIdx.x * 256 + threadIdx.x;   // SEQ * 32 * 64 total
    int d = t & 63;
    int hh = (t >> 6) & 31;
    int s = t >> 11;
    float c0 = cosb[s * 128 + d], sn0 = sinb[s * 128 + d];
    float c1 = cosb[s * 128 + d + 64], sn1 = sinb[s * 128 + d + 64];
    bf16_t* p;
    if (hh < NHEADS) p = qkv + (size_t)s * QKV_LD + hh * HDIM;
    else             p = qkv + (size_t)s * QKV_LD + HIDDEN + (hh - NHEADS) * HDIM;
    float x0 = (float)p[d], x1 = (float)p[d + 64];
    p[d]      = (bf16_t)(x0 * c0 - x1 * sn0);
    p[d + 64] = (bf16_t)(x1 * c1 + x0 * sn1);
}

// ---------------- Flash attention v2: paired q-tiles, KV tile 64, padded LDS ----------------
// grid (16, NHEADS); block 256 = 4 waves; block p handles q-tiles {p, 31-p} (64 rows each)
__global__ __launch_bounds__(256) void attn_kernel(
    const bf16_t* __restrict__ qkv, bf16_t* __restrict__ o_out) {
    __shared__ __align__(16) bf16_t Ks[64][130];   // kv x d, odd-dword row stride (65)
    __shared__ __align__(16) bf16_t Vt[128][66];   // d x kv, odd-dword row stride (33)
    __shared__ __align__(16) bf16_t Pb[4][16][66]; // per-wave P tile, padded
    const int tid = threadIdx.x;
    const int w = tid >> 6, lane = tid & 63;
    const int quad = lane >> 4, l16 = lane & 15;
    const int h = blockIdx.y, kvh = h / GROUPS;
    const int pr = blockIdx.x;
    const bf16_t* qp = qkv + h * HDIM;
    const bf16_t* kp = qkv + HIDDEN + kvh * HDIM;
    const bf16_t* vp = qkv + HIDDEN + 512 + kvh * HDIM;

    for (int sub = 0; sub < 2; ++sub) {
        const int qb = sub ? (31 - pr) : pr;
        const int ntk = qb + 1;
        const int row_q = qb * 64 + w * 16 + l16;
        bf16x8 qa[4];
#pragma unroll
        for (int kc = 0; kc < 4; ++kc)
            qa[kc] = *(const bf16x8*)(qp + (size_t)row_q * QKV_LD + kc * 32 + quad * 8);
        f32x4 o[8] = {};
        float m_r[4], l_r[4];
#pragma unroll
        for (int r = 0; r < 4; ++r) { m_r[r] = -1.0e30f; l_r[r] = 0.f; }

        for (int it = 0; it < ntk; ++it) {
            const int kv0 = it * 64;
            __syncthreads();
            // K stage: thread -> rows w*4+16i+quad, col chunk l16 (coalesced, ~2-way banks)
#pragma unroll
            for (int i = 0; i < 4; ++i) {
                int r = w * 4 + 16 * i + quad;
                *(int4*)&Ks[r][l16 * 8] = *(const int4*)(kp + (size_t)(kv0 + r) * QKV_LD + l16 * 8);
            }
            // V stage transposed: lane = kv row -> scalar stores hit all 32 banks
#pragma unroll
            for (int i = 0; i < 4; ++i) {
                int c8 = w + 4 * i;
                int4 t = *(const int4*)(vp + (size_t)(kv0 + lane) * QKV_LD + c8 * 8);
                bf16_t* ts = (bf16_t*)&t;
#pragma unroll
                for (int i2 = 0; i2 < 8; ++i2) Vt[c8 * 8 + i2][lane] = ts[i2];
            }
            __syncthreads();
            // S = Q K^T : 4 16x16 C-frags covering kv 0..63
            f32x4 s[4] = {};
#pragma unroll
            for (int kc = 0; kc < 4; ++kc)
#pragma unroll
                for (int st = 0; st < 4; ++st) {
                    bf16x8 kb = *(const bf16x8*)&Ks[st * 16 + l16][kc * 32 + quad * 8];
                    s[st] = mfma16(qa[kc], kb, s[st]);
                }
            // online softmax in log2 domain
            const bool diag = (it == ntk - 1);
            float x[4][4], mx[4];
#pragma unroll
            for (int r = 0; r < 4; ++r) {
                int rowg = qb * 64 + w * 16 + quad * 4 + r;
#pragma unroll
                for (int st = 0; st < 4; ++st) {
                    float xv = s[st][r] * SCL_LOG2;
                    if (diag && (kv0 + st * 16 + l16 > rowg)) xv = -1.0e30f;
                    x[r][st] = xv;
                }
                mx[r] = fmaxf(fmaxf(x[r][0], x[r][1]), fmaxf(x[r][2], x[r][3]));
            }
#pragma unroll
            for (int off = 1; off < 16; off <<= 1)
#pragma unroll
                for (int r = 0; r < 4; ++r)
                    mx[r] = fmaxf(mx[r], __shfl_xor(mx[r], off));
            float al[4], rs[4], p[4][4];
#pragma unroll
            for (int r = 0; r < 4; ++r) {
                float mn = fmaxf(m_r[r], mx[r]);
                al[r] = __builtin_amdgcn_exp2f(m_r[r] - mn);
                m_r[r] = mn;
#pragma unroll
                for (int st = 0; st < 4; ++st) p[r][st] = __builtin_amdgcn_exp2f(x[r][st] - mn);
                rs[r] = (p[r][0] + p[r][1]) + (p[r][2] + p[r][3]);
            }
#pragma unroll
            for (int off = 1; off < 16; off <<= 1)
#pragma unroll
                for (int r = 0; r < 4; ++r)
                    rs[r] += __shfl_xor(rs[r], off);
#pragma unroll
            for (int r = 0; r < 4; ++r) l_r[r] = al[r] * l_r[r] + rs[r];
#pragma unroll
            for (int nc = 0; nc < 8; ++nc)
#pragma unroll
                for (int r = 0; r < 4; ++r) o[nc][r] *= al[r];
            // P: C-layout -> LDS -> A-layout (wave-local)
#pragma unroll
            for (int r = 0; r < 4; ++r)
#pragma unroll
                for (int st = 0; st < 4; ++st)
                    Pb[w][quad * 4 + r][st * 16 + l16] = (bf16_t)p[r][st];
            bf16x8 pa0 = *(const bf16x8*)&Pb[w][l16][quad * 8];
            bf16x8 pa1 = *(const bf16x8*)&Pb[w][l16][32 + quad * 8];
#pragma unroll
            for (int nc = 0; nc < 8; ++nc) {
                bf16x8 vb0 = *(const bf16x8*)&Vt[nc * 16 + l16][quad * 8];
                bf16x8 vb1 = *(const bf16x8*)&Vt[nc * 16 + l16][32 + quad * 8];
                o[nc] = mfma16(pa1, vb1, mfma16(pa0, vb0, o[nc]));
            }
        }
        // normalize + store
#pragma unroll
        for (int nc = 0; nc < 8; ++nc)
#pragma unroll
            for (int r = 0; r < 4; ++r) {
                int rowg = qb * 64 + w * 16 + quad * 4 + r;
                int col = h * HDIM + nc * 16 + l16;
                o_out[(size_t)rowg * HIDDEN + col] = (bf16_t)(o[nc][r] / l_r[r]);
            }
    }
}

extern "C" void kernel_launch(void* const* d_in, const int* in_sizes, int n_in,
                              void* d_out, int out_size, void* d_ws, size_t ws_size,
                              hipStream_t stream) {
    const float* hs   = (const float*)d_in[0];
    const float* cosb = (const float*)d_in[1];
    const float* sinb = (const float*)d_in[2];
    const float* Wq   = (const float*)d_in[3];
    const float* bq   = (const float*)d_in[4];
    const float* Wk   = (const float*)d_in[5];
    const float* bk   = (const float*)d_in[6];
    const float* Wv   = (const float*)d_in[7];
    const float* bv   = (const float*)d_in[8];
    const float* Wo   = (const float*)d_in[9];
    float* out = (float*)d_out;

    char* p = (char*)d_ws;
    bf16_t* hsb   = (bf16_t*)p; p += (size_t)SEQ * HIDDEN * 2;        // also reused as attn out
    bf16_t* Wqkvb = (bf16_t*)p; p += (size_t)QKV_LD * HIDDEN * 2;
    bf16_t* Wob   = (bf16_t*)p; p += (size_t)HIDDEN * HIDDEN * 2;
    bf16_t* qkvb  = (bf16_t*)p; p += (size_t)SEQ * QKV_LD * 2;
    float*  bcat  = (float*)p;  p += (size_t)QKV_LD * 4;

    auto cvt = [&](const float* s, bf16_t* d, size_t n) {
        int n4 = (int)(n / 4);
        cvt_kernel<<<(n4 + 255) / 256, 256, 0, stream>>>(s, d, n4);
    };
    cvt(hs, hsb, (size_t)SEQ * HIDDEN);
    cvt(Wq, Wqkvb, (size_t)HIDDEN * HIDDEN);
    cvt(Wk, Wqkvb + (size_t)HIDDEN * HIDDEN, (size_t)512 * HIDDEN);
    cvt(Wv, Wqkvb + (size_t)(HIDDEN + 512) * HIDDEN, (size_t)512 * HIDDEN);
    cvt(Wo, Wob, (size_t)HIDDEN * HIDDEN);
    bcat_kernel<<<(QKV_LD + 255) / 256, 256, 0, stream>>>(bq, bk, bv, bcat);

    gemm_bt<true><<<dim3(QKV_LD / 128, SEQ / 128), 256, 0, stream>>>(
        hsb, Wqkvb, bcat, qkvb, SEQ, QKV_LD, HIDDEN);

    rope_kernel<<<(SEQ * 32 * 64) / 256, 256, 0, stream>>>(qkvb, cosb, sinb);

    attn_kernel<<<dim3(16, NHEADS), 256, 0, stream>>>(qkvb, hsb);

    gemm_bt<false><<<dim3(HIDDEN / 128, SEQ / 128), 256, 0, stream>>>(
        hsb, Wob, nullptr, out, SEQ, HIDDEN, HIDDEN);
}

// Round 3
// 537.082 us; speedup vs baseline: 1.9237x; 1.0399x over previous
//
#include <hip/hip_runtime.h>
#include <hip/hip_bf16.h>

typedef __bf16 bf16_t;
typedef __bf16 bf16x8 __attribute__((ext_vector_type(8)));
typedef __bf16 bf16x4v __attribute__((ext_vector_type(4)));
typedef float f32x4 __attribute__((ext_vector_type(4)));

#define HIDDEN 3584
#define SEQ 2048
#define NHEADS 28
#define NKV 4
#define HDIM 128
#define GROUPS 7
#define QKV_LD 4608
#define SCL_LOG2 (0.08838834764831845f * 1.44269504088896f)

__device__ inline f32x4 mfma16(bf16x8 a, bf16x8 b, f32x4 c) {
    return __builtin_amdgcn_mfma_f32_16x16x32_bf16(a, b, c, 0, 0, 0);
}

__device__ inline void gl_lds16(const bf16_t* g, bf16_t* l) {
    __builtin_amdgcn_global_load_lds(
        (const __attribute__((address_space(1))) void*)g,
        (__attribute__((address_space(3))) void*)l, 16, 0, 0);
}

// ---------------- fp32 -> bf16 convert ----------------
__global__ void cvt_kernel(const float* __restrict__ src, bf16_t* __restrict__ dst, int n4) {
    int i = blockIdx.x * 256 + threadIdx.x;
    if (i < n4) {
        float4 f = ((const float4*)src)[i];
        bf16x4v o;
        o.x = (bf16_t)f.x; o.y = (bf16_t)f.y; o.z = (bf16_t)f.z; o.w = (bf16_t)f.w;
        ((bf16x4v*)dst)[i] = o;
    }
}

// ---------------- bias concat (bq|bk|bv) ----------------
__global__ void bcat_kernel(const float* __restrict__ bq, const float* __restrict__ bk,
                            const float* __restrict__ bv, float* __restrict__ dst) {
    int i = blockIdx.x * 256 + threadIdx.x;
    if (i < QKV_LD) {
        float v = (i < HIDDEN) ? bq[i] : (i < HIDDEN + 512 ? bk[i - HIDDEN] : bv[i - HIDDEN - 512]);
        dst[i] = v;
    }
}

// ---------------- GEMM: C[M,N] = A[M,K] @ B[N,K]^T (+bias) ----------------
template <bool OUT_BF16>
__global__ __launch_bounds__(256) void gemm_bt(
    const bf16_t* __restrict__ A, const bf16_t* __restrict__ B,
    const float* __restrict__ bias, void* __restrict__ Cout,
    int M, int N, int K) {
    __shared__ __align__(16) bf16_t As[128 * 32];
    __shared__ __align__(16) bf16_t Bs[128 * 32];
    const int tid = threadIdx.x;
    const int w = tid >> 6, lane = tid & 63;
    const int quad = lane >> 4, l16 = lane & 15;
    const int wm = w >> 1, wn = w & 1;
    const int m0 = blockIdx.y * 128, n0 = blockIdx.x * 128;
    f32x4 acc[4][4] = {};
    for (int k0 = 0; k0 < K; k0 += 32) {
        __syncthreads();
#pragma unroll
        for (int i = 0; i < 2; ++i) {
            int ca = (w * 2 + i) * 64 + lane;
            int row = ca >> 2, kc = ca & 3;
            gl_lds16(A + (size_t)(m0 + row) * K + k0 + kc * 8, As + (size_t)(w * 2 + i) * 64 * 8);
            gl_lds16(B + (size_t)(n0 + row) * K + k0 + kc * 8, Bs + (size_t)(w * 2 + i) * 64 * 8);
        }
        __syncthreads();
        bf16x8 a[4], b[4];
#pragma unroll
        for (int i = 0; i < 4; ++i)
            a[i] = *(const bf16x8*)(As + (wm * 64 + i * 16 + l16) * 32 + quad * 8);
#pragma unroll
        for (int j = 0; j < 4; ++j)
            b[j] = *(const bf16x8*)(Bs + (wn * 64 + j * 16 + l16) * 32 + quad * 8);
#pragma unroll
        for (int i = 0; i < 4; ++i)
#pragma unroll
            for (int j = 0; j < 4; ++j)
                acc[i][j] = mfma16(a[i], b[j], acc[i][j]);
    }
#pragma unroll
    for (int i = 0; i < 4; ++i) {
#pragma unroll
        for (int j = 0; j < 4; ++j) {
            int col = n0 + wn * 64 + j * 16 + l16;
            float bv_ = bias ? bias[col] : 0.f;
#pragma unroll
            for (int r = 0; r < 4; ++r) {
                int row = m0 + wm * 64 + i * 16 + quad * 4 + r;
                float v = acc[i][j][r] + bv_;
                if (OUT_BF16) ((bf16_t*)Cout)[(size_t)row * N + col] = (bf16_t)v;
                else          ((float*)Cout)[(size_t)row * N + col] = v;
            }
        }
    }
}

// ---------------- RoPE (in-place on bf16 qkv buffer) ----------------
__global__ void rope_kernel(bf16_t* __restrict__ qkv,
                            const float* __restrict__ cosb, const float* __restrict__ sinb) {
    int t = blockIdx.x * 256 + threadIdx.x;   // SEQ * 32 * 64 total
    int d = t & 63;
    int hh = (t >> 6) & 31;
    int s = t >> 11;
    float c0 = cosb[s * 128 + d], sn0 = sinb[s * 128 + d];
    float c1 = cosb[s * 128 + d + 64], sn1 = sinb[s * 128 + d + 64];
    bf16_t* p;
    if (hh < NHEADS) p = qkv + (size_t)s * QKV_LD + hh * HDIM;
    else             p = qkv + (size_t)s * QKV_LD + HIDDEN + (hh - NHEADS) * HDIM;
    float x0 = (float)p[d], x1 = (float)p[d + 64];
    p[d]      = (bf16_t)(x0 * c0 - x1 * sn0);
    p[d + 64] = (bf16_t)(x1 * c1 + x0 * sn1);
}

// ---------------- Flash attention v3: S^T form, no P round-trip, reg-prefetch ----------------
// grid (16, NHEADS); 4 waves; block p handles q-tiles {p, 31-p} (64 rows each)
// kv fragment-row permutation: F(st,m) = 32*(st>>1) + 8*(m>>2) + 4*(st&1) + (m&3)
__global__ __launch_bounds__(256) void attn_kernel(
    const bf16_t* __restrict__ qkv, bf16_t* __restrict__ o_out) {
    __shared__ __align__(16) bf16_t Ks[64][130];   // kv x d, odd-dword row stride (65)
    __shared__ __align__(16) bf16_t Vt[128][66];   // d x kv, odd-dword row stride (33)
    const int tid = threadIdx.x;
    const int w = tid >> 6, lane = tid & 63;
    const int quad = lane >> 4, l16 = lane & 15;
    const int h = blockIdx.y, kvh = h / GROUPS;
    const int pr = blockIdx.x;
    const bf16_t* qp = qkv + h * HDIM;
    const bf16_t* kp = qkv + HIDDEN + kvh * HDIM;
    const bf16_t* vp = qkv + HIDDEN + 512 + kvh * HDIM;
    // permuted A-row (kv) index for QK^T fragment st: F(st, l16)
    int frow[4];
#pragma unroll
    for (int st = 0; st < 4; ++st)
        frow[st] = 32 * (st >> 1) + 8 * (l16 >> 2) + 4 * (st & 1) + (l16 & 3);

    for (int sub = 0; sub < 2; ++sub) {
        const int qb = sub ? (31 - pr) : pr;
        const int ntk = qb + 1;
        const int rowq = qb * 64 + w * 16 + l16;   // this lane's q-row (as column of S^T)
        bf16x8 qa[4];
#pragma unroll
        for (int kc = 0; kc < 4; ++kc)
            qa[kc] = *(const bf16x8*)(qp + (size_t)rowq * QKV_LD + kc * 32 + quad * 8);
        f32x4 o[8] = {};
        float m_r = -1.0e30f, l_r = 0.f;

        int4 kr[4], vr[4];
        auto loadT = [&](int kv0) {
#pragma unroll
            for (int i = 0; i < 4; ++i)
                kr[i] = *(const int4*)(kp + (size_t)(kv0 + w * 4 + 16 * i + quad) * QKV_LD + l16 * 8);
#pragma unroll
            for (int i = 0; i < 4; ++i)
                vr[i] = *(const int4*)(vp + (size_t)(kv0 + lane) * QKV_LD + (w + 4 * i) * 8);
        };
        loadT(0);

        for (int it = 0; it < ntk; ++it) {
            const int kv0 = it * 64;
            __syncthreads();
            // regs -> LDS
#pragma unroll
            for (int i = 0; i < 4; ++i)
                *(int4*)&Ks[w * 4 + 16 * i + quad][l16 * 8] = kr[i];
#pragma unroll
            for (int i = 0; i < 4; ++i) {
                int c8 = w + 4 * i;
                bf16_t* ts = (bf16_t*)&vr[i];
#pragma unroll
                for (int i2 = 0; i2 < 8; ++i2) Vt[c8 * 8 + i2][lane] = ts[i2];
            }
            __syncthreads();
            if (it + 1 < ntk) loadT(kv0 + 64);   // prefetch overlaps compute below
            // S^T = K Q^T : 4 C-frags [kv(permuted) x q]
            f32x4 s[4] = {};
#pragma unroll
            for (int kc = 0; kc < 4; ++kc)
#pragma unroll
                for (int st = 0; st < 4; ++st) {
                    bf16x8 kb = *(const bf16x8*)&Ks[frow[st]][kc * 32 + quad * 8];
                    s[st] = mfma16(kb, qa[kc], s[st]);
                }
            // softmax (log2 domain); row stats live per-lane for q=l16
            const bool diag = (it == ntk - 1);
            float xv[4][4], mx = -1.0e30f;
#pragma unroll
            for (int st = 0; st < 4; ++st)
#pragma unroll
                for (int r = 0; r < 4; ++r) {
                    int kvg = kv0 + 32 * (st >> 1) + 8 * quad + 4 * (st & 1) + r;
                    float x = s[st][r] * SCL_LOG2;
                    if (diag && kvg > rowq) x = -1.0e30f;
                    xv[st][r] = x;
                    mx = fmaxf(mx, x);
                }
            mx = fmaxf(mx, __shfl_xor(mx, 16));
            mx = fmaxf(mx, __shfl_xor(mx, 32));
            float mn = fmaxf(m_r, mx);
            float al = __builtin_amdgcn_exp2f(m_r - mn);
            m_r = mn;
            float rs = 0.f;
            bf16x8 pb0, pb1;
#pragma unroll
            for (int r = 0; r < 4; ++r) {
                float p00 = __builtin_amdgcn_exp2f(xv[0][r] - mn);
                float p01 = __builtin_amdgcn_exp2f(xv[1][r] - mn);
                float p10 = __builtin_amdgcn_exp2f(xv[2][r] - mn);
                float p11 = __builtin_amdgcn_exp2f(xv[3][r] - mn);
                rs += (p00 + p01) + (p10 + p11);
                pb0[r] = (bf16_t)p00; pb0[4 + r] = (bf16_t)p01;
                pb1[r] = (bf16_t)p10; pb1[4 + r] = (bf16_t)p11;
            }
            rs += __shfl_xor(rs, 16);
            rs += __shfl_xor(rs, 32);
            l_r = al * l_r + rs;
            // O^T = V^T P^T : rescale then accumulate (P^T feeds B directly)
#pragma unroll
            for (int dd = 0; dd < 8; ++dd) {
#pragma unroll
                for (int r = 0; r < 4; ++r) o[dd][r] *= al;
                bf16x8 va0 = *(const bf16x8*)&Vt[dd * 16 + l16][quad * 8];
                bf16x8 va1 = *(const bf16x8*)&Vt[dd * 16 + l16][32 + quad * 8];
                o[dd] = mfma16(va1, pb1, mfma16(va0, pb0, o[dd]));
            }
        }
        // epilogue: O^T C-layout -> out[q][d]; lane has 4 consecutive d for q=l16
        float inv_l = 1.0f / l_r;
#pragma unroll
        for (int dd = 0; dd < 8; ++dd) {
            bf16x4v ov;
#pragma unroll
            for (int r = 0; r < 4; ++r) ov[r] = (bf16_t)(o[dd][r] * inv_l);
            *(bf16x4v*)&o_out[(size_t)rowq * HIDDEN + h * HDIM + dd * 16 + quad * 4] = ov;
        }
    }
}

extern "C" void kernel_launch(void* const* d_in, const int* in_sizes, int n_in,
                              void* d_out, int out_size, void* d_ws, size_t ws_size,
                              hipStream_t stream) {
    const float* hs   = (const float*)d_in[0];
    const float* cosb = (const float*)d_in[1];
    const float* sinb = (const float*)d_in[2];
    const float* Wq   = (const float*)d_in[3];
    const float* bq   = (const float*)d_in[4];
    const float* Wk   = (const float*)d_in[5];
    const float* bk   = (const float*)d_in[6];
    const float* Wv   = (const float*)d_in[7];
    const float* bv   = (const float*)d_in[8];
    const float* Wo   = (const float*)d_in[9];
    float* out = (float*)d_out;

    char* p = (char*)d_ws;
    bf16_t* hsb   = (bf16_t*)p; p += (size_t)SEQ * HIDDEN * 2;        // also reused as attn out
    bf16_t* Wqkvb = (bf16_t*)p; p += (size_t)QKV_LD * HIDDEN * 2;
    bf16_t* Wob   = (bf16_t*)p; p += (size_t)HIDDEN * HIDDEN * 2;
    bf16_t* qkvb  = (bf16_t*)p; p += (size_t)SEQ * QKV_LD * 2;
    float*  bcat  = (float*)p;  p += (size_t)QKV_LD * 4;

    auto cvt = [&](const float* s, bf16_t* d, size_t n) {
        int n4 = (int)(n / 4);
        cvt_kernel<<<(n4 + 255) / 256, 256, 0, stream>>>(s, d, n4);
    };
    cvt(hs, hsb, (size_t)SEQ * HIDDEN);
    cvt(Wq, Wqkvb, (size_t)HIDDEN * HIDDEN);
    cvt(Wk, Wqkvb + (size_t)HIDDEN * HIDDEN, (size_t)512 * HIDDEN);
    cvt(Wv, Wqkvb + (size_t)(HIDDEN + 512) * HIDDEN, (size_t)512 * HIDDEN);
    cvt(Wo, Wob, (size_t)HIDDEN * HIDDEN);
    bcat_kernel<<<(QKV_LD + 255) / 256, 256, 0, stream>>>(bq, bk, bv, bcat);

    gemm_bt<true><<<dim3(QKV_LD / 128, SEQ / 128), 256, 0, stream>>>(
        hsb, Wqkvb, bcat, qkvb, SEQ, QKV_LD, HIDDEN);

    rope_kernel<<<(SEQ * 32 * 64) / 256, 256, 0, stream>>>(qkvb, cosb, sinb);

    attn_kernel<<<dim3(16, NHEADS), 256, 0, stream>>>(qkvb, hsb);

    gemm_bt<false><<<dim3(HIDDEN / 128, SEQ / 128), 256, 0, stream>>>(
        hsb, Wob, nullptr, out, SEQ, HIDDEN, HIDDEN);
}